// Round 5
// baseline (864.631 us; speedup 1.0000x reference)
//
#include <hip/hip_runtime.h>
#include <math.h>

#define N_RES 8192
#define N_IN  256
#define BATCH 16

// ---- 2D binning parameters ----
#define NCR       16          // col ranges
#define NRR       16          // row ranges
#define NBKT_MAIN 256         // NRR * NCR
#define NBKT      272         // + 16 input (row-range) buckets
#define CAP_M     28672       // main bucket capacity (mean 26214, +15 sigma)
#define CAP_I     16128       // input bucket capacity (mean 13107, +27 sigma)
#define RR        512         // rows per range
#define CC        512         // cols per range

#define B2_TPB  512
#define B2_ITER 8
#define B2_TILE (B2_TPB * B2_ITER)   // 4096

#define A3_TPB 512
#define NS     2                      // slices per bucket

// raw LDS float atomic add (fire-and-forget ds_add_f32)
__device__ __forceinline__ void lds_fadd(float* p, float v) {
    unsigned a = (unsigned)(uintptr_t)p;
    asm volatile("ds_add_f32 %0, %1" : : "v"(a), "v"(v));
}

// ---------------------------------------------------------------------------
// init: z_acc = bias bcast; state_T/x_T transposes; zero counters
// ---------------------------------------------------------------------------
__global__ void init_kernel(const float* __restrict__ state,
                            const float* __restrict__ x,
                            const float* __restrict__ bias,
                            float* __restrict__ z_acc,
                            float* __restrict__ state_T,
                            float* __restrict__ x_T,
                            int* __restrict__ gcount) {
    int i = blockIdx.x * blockDim.x + threadIdx.x;
    if (i < N_RES * BATCH) {
        int r = i >> 4;
        int b = i & 15;
        state_T[i] = state[b * N_RES + r];
        z_acc[i]   = bias[r];
    }
    if (i < N_IN * BATCH) {
        int c = i >> 4;
        int b = i & 15;
        x_T[i] = x[b * N_IN + c];
    }
    if (i < 512) gcount[i] = 0;
}

// ---------------------------------------------------------------------------
// bin2d: one tile (4096 entries) per block. Wave-private histograms (no
// same-address rtn-atomic serialization), block scan, LDS reorder, coalesced
// bucket writes. Entry = {val, meta = drow<<9 | dcol}.
// ---------------------------------------------------------------------------
__global__ __launch_bounds__(B2_TPB)
void bin2d_kernel(const float* __restrict__ rv,
                  const int*   __restrict__ rrow,
                  const int*   __restrict__ rcol,
                  const float* __restrict__ iv,
                  const int*   __restrict__ irow,
                  const int*   __restrict__ icol,
                  float2* __restrict__ bucket,      // [256][CAP_M]
                  float2* __restrict__ in_bucket,   // [16][CAP_I]
                  int*    __restrict__ gcount,      // [NBKT]
                  int nnz_res, int nnz_total) {
    __shared__ int whist[8][NBKT];   // per-wave counts -> in-place excl. wave bases
    __shared__ int tot[NBKT];
    __shared__ int sc[NBKT];         // inclusive scan of tot
    __shared__ int gbase[NBKT];
    __shared__ float2 stage[B2_TILE];

    const int tid  = threadIdx.x;
    const int wave = tid >> 6;
    const int base = blockIdx.x * B2_TILE;

    for (int i = tid; i < 8 * NBKT; i += B2_TPB) (&whist[0][0])[i] = 0;
    __syncthreads();

    float    ev[B2_ITER];
    unsigned em[B2_ITER];
    int      ebk[B2_ITER];
    int      esl[B2_ITER];
    #pragma unroll
    for (int j = 0; j < B2_ITER; ++j) {
        int idx = base + j * B2_TPB + tid;
        ebk[j] = -1;
        if (idx < nnz_total) {
            float v; int r, c, bk; unsigned m;
            if (idx < nnz_res) {
                v = rv[idx]; r = rrow[idx]; c = rcol[idx];
                bk = ((r >> 9) << 4) | (c >> 9);
                m  = ((unsigned)(r & 511) << 9) | (unsigned)(c & 511);
            } else {
                int k2 = idx - nnz_res;
                v = iv[k2]; r = irow[k2]; c = icol[k2];
                bk = NBKT_MAIN + (r >> 9);
                m  = ((unsigned)(r & 511) << 9) | (unsigned)c;
            }
            ev[j] = v; em[j] = m; ebk[j] = bk;
            esl[j] = atomicAdd(&whist[wave][bk], 1);   // wave-private: pipelined
        }
    }
    __syncthreads();

    // per range: exclusive wave bases (in place) + range totals
    if (tid < NBKT) {
        int s = 0;
        #pragma unroll
        for (int w = 0; w < 8; ++w) { int t = whist[w][tid]; whist[w][tid] = s; s += t; }
        tot[tid] = s; sc[tid] = s;
    }
    __syncthreads();
    // inclusive scan over 272 ranges (Hillis-Steele)
    for (int off = 1; off < NBKT; off <<= 1) {
        int v = 0;
        if (tid < NBKT && tid >= off) v = sc[tid - off];
        __syncthreads();
        if (tid < NBKT) sc[tid] += v;
        __syncthreads();
    }
    if (tid < NBKT) {
        int t = tot[tid];
        if (t > 0) gbase[tid] = atomicAdd(&gcount[tid], t);
    }
    __syncthreads();

    // reorder into stage
    #pragma unroll
    for (int j = 0; j < B2_ITER; ++j)
        if (ebk[j] >= 0) {
            int bk = ebk[j];
            int slot = (sc[bk] - tot[bk]) + whist[wave][bk] + esl[j];
            stage[slot] = make_float2(ev[j], __uint_as_float(em[j]));
        }
    __syncthreads();

    // coalesced bucket writes
    const int tot_all = sc[NBKT - 1];
    for (int k = tid; k < tot_all; k += B2_TPB) {
        int lo = 0;   // largest lo with tbase[lo] <= k  (tbase = sc - tot, monotone)
        #pragma unroll
        for (int step = 256; step >= 1; step >>= 1) {
            int cand = lo + step;
            if (cand < NBKT && (sc[cand] - tot[cand]) <= k) lo = cand;
        }
        int off2 = k - (sc[lo] - tot[lo]);
        int go = gbase[lo] + off2;
        if (lo < NBKT_MAIN) {
            if (go < CAP_M) bucket[(size_t)lo * CAP_M + go] = stage[k];
        } else {
            if (go < CAP_I) in_bucket[(size_t)(lo - NBKT_MAIN) * CAP_I + go] = stage[k];
        }
    }
}

// ---------------------------------------------------------------------------
// accum3: block = (bucket, slice). State col-slice in LDS; streamed bucket
// reads are the ONLY global loads; LDS gather + ds_add; one coalesced flush.
// ---------------------------------------------------------------------------
__device__ __forceinline__ void proc_main(float2 e, int lane,
                                          const float* __restrict__ ls,
                                          float* __restrict__ zl) {
    unsigned u = __float_as_uint(e.y);
    float s = ls[(int)((u & 511u) << 4) + lane];
    lds_fadd(&zl[(int)((u >> 9) << 4) + lane], e.x * s);
}

__global__ __launch_bounds__(A3_TPB)
void accum3_kernel(const float2* __restrict__ bucket,
                   const int*    __restrict__ gcount,
                   const float*  __restrict__ state_T,
                   float* __restrict__ z_acc) {
    __shared__ float ls[CC * BATCH];   // 32 KB state col-slice
    __shared__ float zl[RR * BATCH];   // 32 KB accumulator
    const int tid   = threadIdx.x;
    const int bkt   = (int)blockIdx.x >> 1;     // 0..255
    const int slice = (int)blockIdx.x & (NS - 1);
    const int rrng  = bkt >> 4;
    const int crng  = bkt & 15;
    const int g     = tid >> 4;
    const int lane  = tid & 15;

    {   // coalesced 32 KB copy of the state slice
        const float4* src = (const float4*)(state_T + ((crng * CC) << 4));
        float4* dst = (float4*)ls;
        #pragma unroll 4
        for (int i = tid; i < CC * BATCH / 4; i += A3_TPB) dst[i] = src[i];
    }
    for (int i = tid; i < RR * BATCH; i += A3_TPB) zl[i] = 0.0f;
    __syncthreads();

    int cnt = gcount[bkt]; if (cnt > CAP_M) cnt = CAP_M;
    int per = (cnt + NS - 1) / NS;
    int start = slice * per;
    int end = start + per; if (end > cnt) end = cnt;
    const float2* bk = bucket + (size_t)bkt * CAP_M;

    int k = start + g;
    for (; k + 96 < end; k += 128) {
        float2 e0 = bk[k];
        float2 e1 = bk[k + 32];
        float2 e2 = bk[k + 64];
        float2 e3 = bk[k + 96];
        proc_main(e0, lane, ls, zl);
        proc_main(e1, lane, ls, zl);
        proc_main(e2, lane, ls, zl);
        proc_main(e3, lane, ls, zl);
    }
    for (; k < end; k += 32) proc_main(bk[k], lane, ls, zl);

    asm volatile("s_waitcnt lgkmcnt(0)");
    __syncthreads();

    const int rbase = rrng * RR;
    const int rot = (crng * 32 + slice * 16) & (RR - 1);
    #pragma unroll
    for (int kk = 0; kk < RR / 32; ++kk) {
        int r = (g + kk * 32 + rot) & (RR - 1);
        unsafeAtomicAdd(&z_acc[((rbase + r) << 4) + lane], zl[(r << 4) + lane]);
    }
}

// ---------------------------------------------------------------------------
// accum_in: input buckets; full x_T (16 KB) in LDS.
// ---------------------------------------------------------------------------
__global__ __launch_bounds__(A3_TPB)
void accum_in_kernel(const float2* __restrict__ in_bucket,
                     const int*    __restrict__ gcount,
                     const float*  __restrict__ x_T,
                     float* __restrict__ z_acc) {
    __shared__ float lx[N_IN * BATCH]; // 16 KB
    __shared__ float zl[RR * BATCH];   // 32 KB
    const int tid   = threadIdx.x;
    const int bkt   = (int)blockIdx.x >> 1;     // 0..15 (row range)
    const int slice = (int)blockIdx.x & 1;
    const int g     = tid >> 4;
    const int lane  = tid & 15;

    {
        const float4* src = (const float4*)x_T;
        float4* dst = (float4*)lx;
        for (int i = tid; i < N_IN * BATCH / 4; i += A3_TPB) dst[i] = src[i];
    }
    for (int i = tid; i < RR * BATCH; i += A3_TPB) zl[i] = 0.0f;
    __syncthreads();

    int cnt = gcount[NBKT_MAIN + bkt]; if (cnt > CAP_I) cnt = CAP_I;
    int per = (cnt + 1) / 2;
    int start = slice * per;
    int end = start + per; if (end > cnt) end = cnt;
    const float2* bk = in_bucket + (size_t)bkt * CAP_I;

    for (int k = start + g; k < end; k += 32) proc_main(bk[k], lane, lx, zl);

    asm volatile("s_waitcnt lgkmcnt(0)");
    __syncthreads();

    const int rbase = bkt * RR;
    const int rot = (slice * 256) & (RR - 1);
    #pragma unroll
    for (int kk = 0; kk < RR / 32; ++kk) {
        int r = (g + kk * 32 + rot) & (RR - 1);
        unsafeAtomicAdd(&z_acc[((rbase + r) << 4) + lane], zl[(r << 4) + lane]);
    }
}

// ---------------------------------------------------------------------------
// fallback (small ws): round-1 global-atomic scatter
// ---------------------------------------------------------------------------
__global__ void scatter_kernel(const float* __restrict__ vals,
                               const int* __restrict__ rows,
                               const int* __restrict__ cols,
                               const float* __restrict__ src_T,
                               float* __restrict__ z_acc,
                               int nnz) {
    int tid = blockIdx.x * blockDim.x + threadIdx.x;
    int g   = tid >> 4;
    int b   = tid & 15;
    int ngroups = (gridDim.x * blockDim.x) >> 4;
    for (int k = g; k < nnz; k += ngroups) {
        float v = vals[k];
        int   r = rows[k];
        int   c = cols[k];
        float s = src_T[(c << 4) + b];
        unsafeAtomicAdd(&z_acc[(r << 4) + b], v * s);
    }
}

// ---------------------------------------------------------------------------
// finish: out[b*N_RES + r] = erf(z_acc[r*16 + b])   (A_LEAK == 1.0)
// ---------------------------------------------------------------------------
__global__ void finish_kernel(const float* __restrict__ z_acc,
                              float* __restrict__ out) {
    int i = blockIdx.x * blockDim.x + threadIdx.x;
    if (i < N_RES * BATCH) {
        int b = i >> 13;
        int r = i & (N_RES - 1);
        out[i] = erff(z_acc[(r << 4) + b]);
    }
}

extern "C" void kernel_launch(void* const* d_in, const int* in_sizes, int n_in,
                              void* d_out, int out_size, void* d_ws, size_t ws_size,
                              hipStream_t stream) {
    const float* state    = (const float*)d_in[0];
    const float* x        = (const float*)d_in[1];
    const float* res_vals = (const float*)d_in[2];
    const int*   res_rows = (const int*)  d_in[3];
    const int*   res_cols = (const int*)  d_in[4];
    const float* res_bias = (const float*)d_in[5];
    const float* in_vals  = (const float*)d_in[6];
    const int*   in_rows  = (const int*)  d_in[7];
    const int*   in_cols  = (const int*)  d_in[8];
    float* out = (float*)d_out;

    float*  ws        = (float*)d_ws;
    float*  z_acc     = ws;                          // 131072 f
    float*  state_T   = z_acc + N_RES * BATCH;       // 131072 f
    float*  x_T       = state_T + N_RES * BATCH;     // 4096 f
    int*    gcount    = (int*)(x_T + N_IN * BATCH);  // 512 ints
    float2* bucket    = (float2*)(gcount + 512);     // 256*CAP_M
    float2* in_bucket = bucket + (size_t)NBKT_MAIN * CAP_M; // 16*CAP_I

    const size_t required = (size_t)(N_RES * BATCH * 2 + N_IN * BATCH + 512) * 4
                          + (size_t)NBKT_MAIN * CAP_M * sizeof(float2)
                          + (size_t)16 * CAP_I * sizeof(float2);

    int nnz_res   = in_sizes[2];
    int nnz_in    = in_sizes[6];
    int nnz_total = nnz_res + nnz_in;

    init_kernel<<<(N_RES * BATCH + 255) / 256, 256, 0, stream>>>(
        state, x, res_bias, z_acc, state_T, x_T, gcount);

    if (ws_size >= required) {
        int tiles = (nnz_total + B2_TILE - 1) / B2_TILE;
        bin2d_kernel<<<tiles, B2_TPB, 0, stream>>>(
            res_vals, res_rows, res_cols, in_vals, in_rows, in_cols,
            bucket, in_bucket, gcount, nnz_res, nnz_total);
        accum3_kernel<<<NBKT_MAIN * NS, A3_TPB, 0, stream>>>(
            bucket, gcount, state_T, z_acc);
        accum_in_kernel<<<16 * 2, A3_TPB, 0, stream>>>(
            in_bucket, gcount, x_T, z_acc);
    } else {
        scatter_kernel<<<2048, 256, 0, stream>>>(
            res_vals, res_rows, res_cols, state_T, z_acc, nnz_res);
        scatter_kernel<<<512, 256, 0, stream>>>(
            in_vals, in_rows, in_cols, x_T, z_acc, nnz_in);
    }

    finish_kernel<<<(N_RES * BATCH + 255) / 256, 256, 0, stream>>>(z_acc, out);
}